// Round 1
// baseline (238.677 us; speedup 1.0000x reference)
//
#include <hip/hip_runtime.h>
#include <math.h>

#define N_HID 128
#define E_PER_REL 200000

// One edge per 32-lane half-wave: each lane loads float4 of h[src], h[dst],
// W[rel] (16B/lane, coalesced inside the 512B row), computes the partial
// triple product, then a 5-step shfl_xor reduction within the half-wave.
__global__ __launch_bounds__(256) void distmult_kernel(
    const float* __restrict__ h,
    const float* __restrict__ W,
    const int* __restrict__ src_idx,
    const int* __restrict__ dst_idx,
    float* __restrict__ out,
    int n_edges)
{
    const int edge = blockIdx.x * (blockDim.x >> 5) + (threadIdx.x >> 5);
    const int lane = threadIdx.x & 31;
    if (edge >= n_edges) return;

    const int rel = edge / E_PER_REL;

    const long long s = (long long)src_idx[edge];  // broadcast load (same addr)
    const long long d = (long long)dst_idx[edge];

    const float4* hu = (const float4*)(h + s * (long long)N_HID);
    const float4* hv = (const float4*)(h + d * (long long)N_HID);
    const float4* wr = (const float4*)(W + rel * N_HID);

    const float4 u = hu[lane];
    const float4 v = hv[lane];
    const float4 w = wr[lane];

    float p = u.x * w.x * v.x
            + u.y * w.y * v.y
            + u.z * w.z * v.z
            + u.w * w.w * v.w;

    // xor masks < 32 keep lanes within their 32-lane half of the wave64
    p += __shfl_xor(p, 16);
    p += __shfl_xor(p, 8);
    p += __shfl_xor(p, 4);
    p += __shfl_xor(p, 2);
    p += __shfl_xor(p, 1);

    if (lane == 0) {
        out[edge] = 1.0f / (1.0f + expf(-p));
    }
}

extern "C" void kernel_launch(void* const* d_in, const int* in_sizes, int n_in,
                              void* d_out, int out_size, void* d_ws, size_t ws_size,
                              hipStream_t stream) {
    const float* h       = (const float*)d_in[0];
    const float* W       = (const float*)d_in[1];
    const int*   src_idx = (const int*)d_in[2];
    const int*   dst_idx = (const int*)d_in[3];
    float*       out     = (float*)d_out;

    const int n_edges = out_size;               // R * E = 1.2M
    const int threads = 256;
    const int edges_per_block = threads / 32;   // 8
    const int grid = (n_edges + edges_per_block - 1) / edges_per_block;

    distmult_kernel<<<grid, threads, 0, stream>>>(h, W, src_idx, dst_idx, out, n_edges);
}